// Round 1
// baseline (1106.562 us; speedup 1.0000x reference)
//
#include <hip/hip_runtime.h>
#include <hip/hip_cooperative_groups.h>

namespace cg = cooperative_groups;

// WaveFDTD2D, persistent cooperative kernel: ALL 512 steps in ONE launch.
// Round 14: rounds 5-13 proved the loop body is not the bottleneck; the
// remaining ~250us of the 362us was launch machinery (dispatch, prologue,
// inter-kernel L2 flush, straggler) x33 launches. This round replaces the
// 33 launches with one hipLaunchCooperativeKernel + 32 grid.sync()s.
//  - grid = 16x16 blocks x 1024 thr = 1 block/CU on 256 CUs; launch_bounds
//    (1024) caps VGPR at 128 -> all blocks co-resident (LDS 33.8KB << 160KB).
//  - init (zero PA/PB, zero out) folded into the prologue; V2 is computed
//    ONCE from vel into 4 registers/thread and never touches global memory.
//  - cone-skipped blocks fall through to grid.sync (no empty dispatches).
//  - per-round structure (padded loads, LDS ping-pong, DPP z-neighbors,
//    source injection, receiver rv[] buffering) copied verbatim from the
//    validated r8/r13 kernel. Cross-round LDS hazard (receiver read of sb[0]
//    at s=15 vs next round's prefill of sb[0]) is ordered by grid.sync().
// Wave w owns field rows 4w..4w+3 at lane=ez; z-neighbors via DPP; x-
// neighbors in registers; flank reads via dummy zero LDS rows (wave-uniform
// ds_read2st64). Rim garbage penetrates s cells/substep from the ext edge;
// interior depth 16 -> never contaminated (validated r3-r13).

#define NXd 512
#define NZd 512
#define NSTEPSd 512
#define NRECd 128
#define DT2f 1.0e-6f
#define INVf 1.0e-2f
#define TBk 16
#define TIk 32
#define EXTk 64
#define NTILEk 16
#define PADk 16
#define PWk 544              // NXd + 2*PADk
#define LROWS 66             // 1 dummy + 64 field rows + 1 dummy

__device__ __forceinline__ float dpp_shr1(float x) {  // lane i <- lane i-1
    int v = __builtin_amdgcn_update_dpp(0, __builtin_bit_cast(int, x),
                                        0x138, 0xF, 0xF, false);  // WAVE_SHR:1
    return __builtin_bit_cast(float, v);
}
__device__ __forceinline__ float dpp_shl1(float x) {  // lane i <- lane i+1
    int v = __builtin_amdgcn_update_dpp(0, __builtin_bit_cast(int, x),
                                        0x130, 0xF, 0xF, false);  // WAVE_SHL:1
    return __builtin_bit_cast(float, v);
}

__global__ __launch_bounds__(1024) void fdtd_persist(
    const float* __restrict__ vel, const float* __restrict__ source,
    const int* __restrict__ src_x, const int* __restrict__ src_z,
    const int* __restrict__ rec_x, const int* __restrict__ rec_z,
    float2* __restrict__ PA, float2* __restrict__ PB,
    float* __restrict__ out)
{
    cg::grid_group gg = cg::this_grid();
    __shared__ float sb[2][LROWS * EXTk];

    const int tid = threadIdx.x;
    const int w   = tid >> 6;       // 16 waves, wave w owns field rows 4w..4w+3
    const int ez  = tid & 63;       // lane -> ext z coord
    const int gx0 = blockIdx.y * TIk;
    const int gz0 = blockIdx.x * TIk;
    const int ox = gx0 - TBk, oz = gz0 - TBk;

    // ---- Prologue / init (replaces fdtd_init kernel) ----
    {
        const int gsz = (int)(gridDim.x * gridDim.y) * (int)blockDim.x; // 262144
        int g = ((int)(blockIdx.y * gridDim.x + blockIdx.x)) * (int)blockDim.x + tid;
        for (int p = g; p < PWk * PWk; p += gsz) {
            PA[p] = make_float2(0.f, 0.f);
            PB[p] = make_float2(0.f, 0.f);
        }
        if (g < NRECd * NSTEPSd) out[g] = 0.f;   // harness re-poisons d_out
    }

    // V2 lives in 4 registers per thread for the whole run: v^2*dt^2/(dx*dz),
    // 0 in the apron (zero BC) -- never stored to global.
    float rV2i[4];
    {
        const int fz = oz + ez;                   // field column
        #pragma unroll
        for (int i = 0; i < 4; ++i) {
            const int fx = ox + 4 * w + i;        // field row
            float v2 = 0.f;
            if (fx >= 0 && fx < NXd && fz >= 0 && fz < NZd) {
                float v = vel[fx * NZd + fz];
                v2 = v * v * (DT2f * INVf);
            }
            rV2i[i] = v2;
        }
    }

    // Dummy LDS rows (0 and 65) zero in BOTH buffers; never rewritten.
    if (w == 0) {
        sb[0][ez] = 0.f;
        sb[0][(LROWS - 1) * EXTk + ez] = 0.f;
        sb[1][ez] = 0.f;
        sb[1][(LROWS - 1) * EXTk + ez] = 0.f;
    }

    // Source ownership (owner = lane ezs of wave exs>>2, register exs&3).
    const int sx = *src_x, sz = *src_z;
    const int exs = sx - ox, ezs = sz - oz;
    const bool srcHere = (exs >= 0 && exs < EXTk && ezs >= 0 && ezs < EXTk) &&
                         (tid == (((exs >> 2) << 6) | ezs));

    // O(1) receiver ownership: thread r collects receiver r from LDS.
    bool rOwn = false; int rIdx = 0;
    if (tid < NRECd) {
        int rx = rec_x[tid], rz = rec_z[tid];
        rOwn = (rx >= gx0 && rx < gx0 + TIk && rz >= gz0 && rz < gz0 + TIk);
        rIdx = (rx - ox + 1) * EXTk + (rz - oz);    // buffer row = field+1
    }

    // Exact L1 cone distance: field identically 0 beyond radius t.
    const int dxm = max(0, max(ox - sx, sx - (ox + EXTk - 1)));
    const int dzm = max(0, max(oz - sz, sz - (oz + EXTk - 1)));
    const int dman = dxm + dzm;

    const int pbase = (gx0 + 4 * w) * PWk + gz0 + ez;  // padded global index
    const int fbase = 4 * w * EXTk + ez;   // buffer row 4w (field row 4w-1)

    gg.sync();   // init visible everywhere

    // ---- 32 rounds x 16 sub-steps; grid.sync replaces kernel boundaries ----
    for (int k = 0; k < NSTEPSd / TBk; ++k) {
        const int t0 = TBk * k;
        if (dman <= t0 + TBk + 1) {               // block-uniform cone check
            const float2* __restrict__ Pin = (k & 1) ? PB : PA;
            float2*       __restrict__ Pout = (k & 1) ? PA : PB;

            // Unconditional padded loads (apron = zeros forever).
            float2 co[4];
            #pragma unroll
            for (int i = 0; i < 4; ++i) co[i] = Pin[pbase + i * PWk];

            // Unpack + prefill LDS buffer 0.
            float rCur[4], rOld[4];
            #pragma unroll
            for (int i = 0; i < 4; ++i) {
                rCur[i] = co[i].x; rOld[i] = co[i].y;
                sb[0][(4 * w + 1 + i) * EXTk + ez] = rCur[i];
            }

            float sv[TBk];
            if (srcHere) {
                #pragma unroll
                for (int s = 0; s < TBk; ++s) sv[s] = source[t0 + s] * DT2f;
            }

            __syncthreads();

            // ---- 16 sub-steps, fully unrolled, no predication ----
            float rv[TBk];
            #pragma unroll
            for (int s = 0; s < TBk; ++s) {
                const float* cur = sb[s & 1];
                float* nxt = sb[(s & 1) ^ 1];
                // Wave-uniform base + const offsets {0, 5*EXTk} -> ds_read2st64:
                // field rows 4w-1 and 4w+4 at column ez (edge waves hit dummies).
                const float up0 = cur[fbase];
                const float dn3 = cur[fbase + 5 * EXTk];
                float nv[4];
                #pragma unroll
                for (int i = 0; i < 4; ++i) {
                    const float up = (i == 0) ? up0 : rCur[i - 1];
                    const float dn = (i == 3) ? dn3 : rCur[i + 1];
                    const float lf = dpp_shr1(rCur[i]);     // z-1 neighbor
                    const float rt = dpp_shl1(rCur[i]);     // z+1 neighbor
                    const float sum = (up + dn) + (lf + rt);
                    const float t4 = __builtin_fmaf(-4.0f, rCur[i], sum);
                    const float pm = __builtin_fmaf(2.0f, rCur[i], -rOld[i]);
                    nv[i] = __builtin_fmaf(rV2i[i], t4, pm);
                }
                #pragma unroll
                for (int i = 0; i < 4; ++i) {
                    rOld[i] = rCur[i];
                    rCur[i] = nv[i];
                    nxt[fbase + (1 + i) * EXTk] = nv[i];    // buffer row 4w+1+i
                }
                // Source injection (post-stencil, pre-recording).
                if (srcHere) {
                    #pragma unroll
                    for (int i = 0; i < 4; ++i) {
                        if (i == (exs & 3)) {
                            rCur[i] += sv[s];
                            nxt[(exs + 1) * EXTk + ezs] = rCur[i];
                        }
                    }
                }
                __syncthreads();
                // Receiver sample of field@t0+s (post-injection). Next substep
                // writes the OTHER buffer -> race-free with one barrier.
                if (rOwn) rv[s] = nxt[rIdx];
            }

            // Store interior (rows 16..47 = waves 4..11, lanes 16..47).
            if (w >= 4 && w < 12 && ez >= TBk && ez < EXTk - TBk) {
                #pragma unroll
                for (int i = 0; i < 4; ++i)
                    Pout[pbase + i * PWk] = make_float2(rCur[i], rOld[i]);
            }

            // Flush receiver buffer (16 contiguous floats).
            if (rOwn) {
                #pragma unroll
                for (int s = 0; s < TBk; ++s)
                    out[tid * NSTEPSd + t0 + s] = rv[s];
            }
        }
        gg.sync();   // interiors of round k visible before round k+1 halos
    }
}

extern "C" void kernel_launch(void* const* d_in, const int* in_sizes, int n_in,
                              void* d_out, int out_size, void* d_ws, size_t ws_size,
                              hipStream_t stream) {
    const float* vel    = (const float*)d_in[0];
    const float* source = (const float*)d_in[1];
    const int*   src_x  = (const int*)d_in[2];
    const int*   src_z  = (const int*)d_in[3];
    const int*   rec_x  = (const int*)d_in[4];
    const int*   rec_z  = (const int*)d_in[5];
    float* out = (float*)d_out;

    const size_t FP = (size_t)PWk * PWk;
    float2* PA = (float2*)d_ws;       // padded (cur, old), set A
    float2* PB = PA + FP;             // set B

    void* args[] = {(void*)&vel, (void*)&source, (void*)&src_x, (void*)&src_z,
                    (void*)&rec_x, (void*)&rec_z, (void*)&PA, (void*)&PB,
                    (void*)&out};
    hipLaunchCooperativeKernel((void*)fdtd_persist, dim3(NTILEk, NTILEk),
                               dim3(1024), args, 0, stream);
}

// Round 2
// 577.090 us; speedup vs baseline: 1.9175x; 1.9175x over previous
//
#include <hip/hip_runtime.h>

// WaveFDTD2D, persistent kernel with NEIGHBORHOOD sync (r15).
// r14 proved launches can be removed but cg::grid_group::sync costs ~30us
// (runtime centralized barrier + s_sleep polling): 32 syncs = ~1ms. This
// round keeps the single cooperative launch (co-residency guarantee only)
// and replaces the grid barrier with per-block phase counters: block (by,bx)
// only exchanges halo (16 cells) with its 8 neighbors (tile 32), so it only
// needs THEIR counters to reach round k before proceeding.
//   publish:  __syncthreads (drains vmcnt) -> __threadfence (wbl2, release)
//             -> atomic store done[b] = k+2   (device scope)
//   wait:     tid<8 poll done[neighbor] >= k+1 (relaxed) -> __threadfence
//             (buffer_inv, acquire) -> __syncthreads
// WAR+RAW both ordered: neighbor publishes k+1 only after its round-(k-1)
// reads AND writes. Init is block-local: each block zeros its own 34x34
// padded patch (544=16*34; any ext-region read touches only patches of the
// 8-neighborhood) and the receiver-owning block zeros its own out rows.
// Cone-skipped prefix published in ONE atomic store (kAct+1, monotone
// semantics); finished blocks just exit -- no global straggler coupling.
// Loop body (padded loads, LDS ping-pong, DPP z-neighbors, source injection,
// receiver rv[] buffering, V2-in-registers) verbatim from validated r13/r14.

#define NXd 512
#define NZd 512
#define NSTEPSd 512
#define NRECd 128
#define DT2f 1.0e-6f
#define INVf 1.0e-2f
#define TBk 16
#define TIk 32
#define EXTk 64
#define NTILEk 16
#define PADk 16
#define PWk 544              // NXd + 2*PADk = 16*34
#define LROWS 66             // 1 dummy + 64 field rows + 1 dummy
#define NROUNDS (NSTEPSd / TBk)

__device__ __forceinline__ float dpp_shr1(float x) {  // lane i <- lane i-1
    int v = __builtin_amdgcn_update_dpp(0, __builtin_bit_cast(int, x),
                                        0x138, 0xF, 0xF, false);  // WAVE_SHR:1
    return __builtin_bit_cast(float, v);
}
__device__ __forceinline__ float dpp_shl1(float x) {  // lane i <- lane i+1
    int v = __builtin_amdgcn_update_dpp(0, __builtin_bit_cast(int, x),
                                        0x130, 0xF, 0xF, false);  // WAVE_SHL:1
    return __builtin_bit_cast(float, v);
}

__global__ __launch_bounds__(1024) void fdtd_persist(
    const float* __restrict__ vel, const float* __restrict__ source,
    const int* __restrict__ src_x, const int* __restrict__ src_z,
    const int* __restrict__ rec_x, const int* __restrict__ rec_z,
    float2* __restrict__ PA, float2* __restrict__ PB,
    float* __restrict__ out, unsigned* __restrict__ done)
{
    __shared__ float sb[2][LROWS * EXTk];

    const int tid = threadIdx.x;
    const int w   = tid >> 6;       // 16 waves, wave w owns field rows 4w..4w+3
    const int ez  = tid & 63;       // lane -> ext z coord
    const int bx = blockIdx.x, by = blockIdx.y;
    const int gx0 = by * TIk;
    const int gz0 = bx * TIk;
    const int ox = gx0 - TBk, oz = gz0 - TBk;
    const int myid = (by * NTILEk + bx) * 32;   // 128B-strided counter slot

    // ---- Block-local init: zero own 34x34 padded patch of PA and PB ----
    for (int i = tid; i < 34 * 34; i += 1024) {
        const int p = (by * 34 + i / 34) * PWk + (bx * 34 + i % 34);
        PA[p] = make_float2(0.f, 0.f);
        PB[p] = make_float2(0.f, 0.f);
    }

    // O(1) receiver ownership; owning block zeros its receivers' out rows
    // (harness re-poisons d_out; rounds where this block is cone-skipped
    // must read back 0, and the zero/sample writes are same-block ordered).
    bool rOwn = false; int rIdx = 0;
    if (tid < NRECd) {
        const int rx = rec_x[tid], rz = rec_z[tid];
        rOwn = (rx >= gx0 && rx < gx0 + TIk && rz >= gz0 && rz < gz0 + TIk);
        rIdx = (rx - ox + 1) * EXTk + (rz - oz);    // buffer row = field+1
        if (rOwn) {
            float4* o4 = (float4*)&out[tid * NSTEPSd];
            #pragma unroll
            for (int j = 0; j < NSTEPSd / 4; ++j) o4[j] = make_float4(0.f, 0.f, 0.f, 0.f);
        }
    }

    // V2 in 4 registers per thread for the whole run: v^2*dt^2/(dx*dz),
    // 0 in the apron (zero BC) -- never touches global memory.
    float rV2i[4];
    {
        const int fz = oz + ez;
        #pragma unroll
        for (int i = 0; i < 4; ++i) {
            const int fx = ox + 4 * w + i;
            float v2 = 0.f;
            if (fx >= 0 && fx < NXd && fz >= 0 && fz < NZd) {
                float v = vel[fx * NZd + fz];
                v2 = v * v * (DT2f * INVf);
            }
            rV2i[i] = v2;
        }
    }

    // Dummy LDS rows (0 and 65) zero in BOTH buffers; never rewritten.
    if (w == 0) {
        sb[0][ez] = 0.f;
        sb[0][(LROWS - 1) * EXTk + ez] = 0.f;
        sb[1][ez] = 0.f;
        sb[1][(LROWS - 1) * EXTk + ez] = 0.f;
    }

    // Source ownership (owner = lane ezs of wave exs>>2, register exs&3).
    const int sx = *src_x, sz = *src_z;
    const int exs = sx - ox, ezs = sz - oz;
    const bool srcHere = (exs >= 0 && exs < EXTk && ezs >= 0 && ezs < EXTk) &&
                         (tid == (((exs >> 2) << 6) | ezs));

    // Exact L1 cone: active at round k iff dman <= 16k+17.
    const int dxm = max(0, max(ox - sx, sx - (ox + EXTk - 1)));
    const int dzm = max(0, max(oz - sz, sz - (oz + EXTk - 1)));
    const int dman = dxm + dzm;
    const int kAct = dman <= (TBk + 1) ? 0 : (dman - (TBk + 1) + TBk - 1) / TBk;

    // My counter slot of each of my 8 neighbors (clamped; clamp->self is
    // always already satisfied since own counter == k+1 entering round k).
    int nb = myid;
    if (tid < 8) {
        const int d = (tid < 4) ? tid : tid + 1;          // skip center
        const int ny = min(NTILEk - 1, max(0, by + d / 3 - 1));
        const int nx = min(NTILEk - 1, max(0, bx + d % 3 - 1));
        nb = (ny * NTILEk + nx) * 32;
    }

    const int pbase = (gx0 + 4 * w) * PWk + gz0 + ez;  // padded global index
    const int fbase = 4 * w * EXTk + ez;   // buffer row 4w (field row 4w-1)

    // Publish init + entire cone-skipped prefix in one release store.
    __syncthreads();                       // drains all waves' vmcnt
    if (tid == 0) {
        __threadfence();                   // wbl2: init visible cross-XCD
        __hip_atomic_store(&done[myid], (unsigned)(kAct + 1),
                           __ATOMIC_RELAXED, __HIP_MEMORY_SCOPE_AGENT);
    }

    // ---- Rounds kAct..31; monotone cone => always active once started ----
    for (int k = kAct; k < NROUNDS; ++k) {
        const int t0 = TBk * k;

        // Wait: 8 neighbors finished round k-1 (reads AND writes).
        if (tid < 8) {
            const unsigned tgt = (unsigned)(k + 1);
            while (__hip_atomic_load(&done[nb], __ATOMIC_RELAXED,
                                     __HIP_MEMORY_SCOPE_AGENT) < tgt)
                __builtin_amdgcn_s_sleep(1);
            __threadfence();               // buffer_inv: acquire
        }
        __syncthreads();

        const float2* __restrict__ Pin  = (k & 1) ? PB : PA;
        float2*       __restrict__ Pout = (k & 1) ? PA : PB;

        // Unconditional padded loads (apron = zeros forever).
        float2 co[4];
        #pragma unroll
        for (int i = 0; i < 4; ++i) co[i] = Pin[pbase + i * PWk];

        // Unpack + prefill LDS buffer 0.
        float rCur[4], rOld[4];
        #pragma unroll
        for (int i = 0; i < 4; ++i) {
            rCur[i] = co[i].x; rOld[i] = co[i].y;
            sb[0][(4 * w + 1 + i) * EXTk + ez] = rCur[i];
        }

        float sv[TBk];
        if (srcHere) {
            #pragma unroll
            for (int s = 0; s < TBk; ++s) sv[s] = source[t0 + s] * DT2f;
        }

        __syncthreads();

        // ---- 16 sub-steps, fully unrolled, no predication ----
        float rv[TBk];
        #pragma unroll
        for (int s = 0; s < TBk; ++s) {
            const float* cur = sb[s & 1];
            float* nxt = sb[(s & 1) ^ 1];
            // Wave-uniform base + const offsets {0, 5*EXTk} -> ds_read2st64:
            // field rows 4w-1 and 4w+4 at column ez (edge waves hit dummies).
            const float up0 = cur[fbase];
            const float dn3 = cur[fbase + 5 * EXTk];
            float nv[4];
            #pragma unroll
            for (int i = 0; i < 4; ++i) {
                const float up = (i == 0) ? up0 : rCur[i - 1];
                const float dn = (i == 3) ? dn3 : rCur[i + 1];
                const float lf = dpp_shr1(rCur[i]);     // z-1 neighbor
                const float rt = dpp_shl1(rCur[i]);     // z+1 neighbor
                const float sum = (up + dn) + (lf + rt);
                const float t4 = __builtin_fmaf(-4.0f, rCur[i], sum);
                const float pm = __builtin_fmaf(2.0f, rCur[i], -rOld[i]);
                nv[i] = __builtin_fmaf(rV2i[i], t4, pm);
            }
            #pragma unroll
            for (int i = 0; i < 4; ++i) {
                rOld[i] = rCur[i];
                rCur[i] = nv[i];
                nxt[fbase + (1 + i) * EXTk] = nv[i];    // buffer row 4w+1+i
            }
            // Source injection (post-stencil, pre-recording).
            if (srcHere) {
                #pragma unroll
                for (int i = 0; i < 4; ++i) {
                    if (i == (exs & 3)) {
                        rCur[i] += sv[s];
                        nxt[(exs + 1) * EXTk + ezs] = rCur[i];
                    }
                }
            }
            __syncthreads();
            // Receiver sample of field@t0+s (post-injection). Next substep
            // writes the OTHER buffer -> race-free with one barrier.
            if (rOwn) rv[s] = nxt[rIdx];
        }

        // Store interior (rows 16..47 = waves 4..11, lanes 16..47).
        if (w >= 4 && w < 12 && ez >= TBk && ez < EXTk - TBk) {
            #pragma unroll
            for (int i = 0; i < 4; ++i)
                Pout[pbase + i * PWk] = make_float2(rCur[i], rOld[i]);
        }

        // Flush receiver buffer (16 contiguous floats).
        if (rOwn) {
            #pragma unroll
            for (int s = 0; s < TBk; ++s)
                out[tid * NSTEPSd + t0 + s] = rv[s];
        }

        // Publish round k (after ALL waves' reads+writes have drained).
        __syncthreads();                   // also orders rv reads vs next prefill
        if (tid == 0) {
            __threadfence();               // wbl2: release
            __hip_atomic_store(&done[myid], (unsigned)(k + 2),
                               __ATOMIC_RELAXED, __HIP_MEMORY_SCOPE_AGENT);
        }
    }
}

extern "C" void kernel_launch(void* const* d_in, const int* in_sizes, int n_in,
                              void* d_out, int out_size, void* d_ws, size_t ws_size,
                              hipStream_t stream) {
    const float* vel    = (const float*)d_in[0];
    const float* source = (const float*)d_in[1];
    const int*   src_x  = (const int*)d_in[2];
    const int*   src_z  = (const int*)d_in[3];
    const int*   rec_x  = (const int*)d_in[4];
    const int*   rec_z  = (const int*)d_in[5];
    float* out = (float*)d_out;

    const size_t FP = (size_t)PWk * PWk;
    float2* PA = (float2*)d_ws;       // padded (cur, old), set A
    float2* PB = PA + FP;             // set B
    unsigned* DONE = (unsigned*)(PB + FP);   // 256 counters, 128B stride

    hipMemsetAsync(DONE, 0, (size_t)NTILEk * NTILEk * 32 * sizeof(unsigned), stream);

    void* args[] = {(void*)&vel, (void*)&source, (void*)&src_x, (void*)&src_z,
                    (void*)&rec_x, (void*)&rec_z, (void*)&PA, (void*)&PB,
                    (void*)&out, (void*)&DONE};
    hipLaunchCooperativeKernel((void*)fdtd_persist, dim3(NTILEk, NTILEk),
                               dim3(1024), args, 0, stream);
}

// Round 3
// 339.969 us; speedup vs baseline: 3.2549x; 1.6975x over previous
//
#include <hip/hip_runtime.h>

// WaveFDTD2D, persistent kernel, FENCELESS neighborhood sync (r16).
// r14: one cooperative launch, grid.sync = ~30us/round -> 1093us.
// r15: 8-neighbor counter sync, but __threadfence (buffer_wbl2 + buffer_inv,
//      full-L2 writeback/invalidate per round per block) left ~13us/round
//      of sync cost -> 505us, VALUBusy 11%.
// r16: route ALL cross-block data through the coherent point instead of
//      cached+flush. Field loads/stores are relaxed AGENT-scope 8B atomics
//      (sc-flagged, bypass non-coherent L1/L2, served by the die-level
//      Infinity Cache which IS cross-XCD coherent). Acquire fence: dropped
//      (no stale cached copy can be consulted). Release fence: dropped
//      (__syncthreads drains each wave's vmcnt store-acks; the agent-scope
//      counter store issues after the barrier -- same proven mechanism the
//      DONE counter itself already uses).
// Everything else verbatim from validated r15: block-local init, exact L1
// cone skip with one-shot prefix publish, LDS ping-pong, DPP z-neighbors,
// x-neighbors in registers, dummy zero LDS rows, V2-in-registers, receiver
// rv[] buffering. out[] writes are block-private (harness reads after
// kernel end -> end-of-kernel writeback covers them).

#define NXd 512
#define NZd 512
#define NSTEPSd 512
#define NRECd 128
#define DT2f 1.0e-6f
#define INVf 1.0e-2f
#define TBk 16
#define TIk 32
#define EXTk 64
#define NTILEk 16
#define PADk 16
#define PWk 544              // NXd + 2*PADk = 16*34
#define LROWS 66             // 1 dummy + 64 field rows + 1 dummy
#define NROUNDS (NSTEPSd / TBk)

__device__ __forceinline__ float dpp_shr1(float x) {  // lane i <- lane i-1
    int v = __builtin_amdgcn_update_dpp(0, __builtin_bit_cast(int, x),
                                        0x138, 0xF, 0xF, false);  // WAVE_SHR:1
    return __builtin_bit_cast(float, v);
}
__device__ __forceinline__ float dpp_shl1(float x) {  // lane i <- lane i+1
    int v = __builtin_amdgcn_update_dpp(0, __builtin_bit_cast(int, x),
                                        0x130, 0xF, 0xF, false);  // WAVE_SHL:1
    return __builtin_bit_cast(float, v);
}

// Coherent-point (agent-scope) 8B field accesses: bypass L1/L2, hit L3.
__device__ __forceinline__ float2 ldg_f2(const float2* p) {
    unsigned long long v = __hip_atomic_load(
        (const unsigned long long*)p, __ATOMIC_RELAXED, __HIP_MEMORY_SCOPE_AGENT);
    return __builtin_bit_cast(float2, v);
}
__device__ __forceinline__ void stg_f2(float2* p, float2 x) {
    __hip_atomic_store((unsigned long long*)p,
                       __builtin_bit_cast(unsigned long long, x),
                       __ATOMIC_RELAXED, __HIP_MEMORY_SCOPE_AGENT);
}

__global__ __launch_bounds__(1024) void fdtd_persist(
    const float* __restrict__ vel, const float* __restrict__ source,
    const int* __restrict__ src_x, const int* __restrict__ src_z,
    const int* __restrict__ rec_x, const int* __restrict__ rec_z,
    float2* __restrict__ PA, float2* __restrict__ PB,
    float* __restrict__ out, unsigned* __restrict__ done)
{
    __shared__ float sb[2][LROWS * EXTk];

    const int tid = threadIdx.x;
    const int w   = tid >> 6;       // 16 waves, wave w owns field rows 4w..4w+3
    const int ez  = tid & 63;       // lane -> ext z coord
    const int bx = blockIdx.x, by = blockIdx.y;
    const int gx0 = by * TIk;
    const int gz0 = bx * TIk;
    const int ox = gx0 - TBk, oz = gz0 - TBk;
    const int myid = (by * NTILEk + bx) * 32;   // 128B-strided counter slot

    // ---- Block-local init: zero own 34x34 padded patch of PA and PB ----
    // Agent stores: neighbors read these in round 0 via agent loads; a
    // normal cached store would sit dirty in the local L2, invisible to them.
    for (int i = tid; i < 34 * 34; i += 1024) {
        const int p = (by * 34 + i / 34) * PWk + (bx * 34 + i % 34);
        stg_f2(&PA[p], make_float2(0.f, 0.f));
        stg_f2(&PB[p], make_float2(0.f, 0.f));
    }

    // O(1) receiver ownership; owning block zeros its receivers' out rows
    // (block-private: only this block ever writes them again).
    bool rOwn = false; int rIdx = 0;
    if (tid < NRECd) {
        const int rx = rec_x[tid], rz = rec_z[tid];
        rOwn = (rx >= gx0 && rx < gx0 + TIk && rz >= gz0 && rz < gz0 + TIk);
        rIdx = (rx - ox + 1) * EXTk + (rz - oz);    // buffer row = field+1
        if (rOwn) {
            float4* o4 = (float4*)&out[tid * NSTEPSd];
            #pragma unroll
            for (int j = 0; j < NSTEPSd / 4; ++j) o4[j] = make_float4(0.f, 0.f, 0.f, 0.f);
        }
    }

    // V2 in 4 registers per thread for the whole run: v^2*dt^2/(dx*dz),
    // 0 in the apron (zero BC) -- never touches global memory.
    float rV2i[4];
    {
        const int fz = oz + ez;
        #pragma unroll
        for (int i = 0; i < 4; ++i) {
            const int fx = ox + 4 * w + i;
            float v2 = 0.f;
            if (fx >= 0 && fx < NXd && fz >= 0 && fz < NZd) {
                float v = vel[fx * NZd + fz];
                v2 = v * v * (DT2f * INVf);
            }
            rV2i[i] = v2;
        }
    }

    // Dummy LDS rows (0 and 65) zero in BOTH buffers; never rewritten.
    if (w == 0) {
        sb[0][ez] = 0.f;
        sb[0][(LROWS - 1) * EXTk + ez] = 0.f;
        sb[1][ez] = 0.f;
        sb[1][(LROWS - 1) * EXTk + ez] = 0.f;
    }

    // Source ownership (owner = lane ezs of wave exs>>2, register exs&3).
    const int sx = *src_x, sz = *src_z;
    const int exs = sx - ox, ezs = sz - oz;
    const bool srcHere = (exs >= 0 && exs < EXTk && ezs >= 0 && ezs < EXTk) &&
                         (tid == (((exs >> 2) << 6) | ezs));

    // Exact L1 cone: active at round k iff dman <= 16k+17.
    const int dxm = max(0, max(ox - sx, sx - (ox + EXTk - 1)));
    const int dzm = max(0, max(oz - sz, sz - (oz + EXTk - 1)));
    const int dman = dxm + dzm;
    const int kAct = dman <= (TBk + 1) ? 0 : (dman - (TBk + 1) + TBk - 1) / TBk;

    // My counter slot of each of my 8 neighbors (clamped; clamp->self is
    // always already satisfied since own counter == k+1 entering round k).
    int nb = myid;
    if (tid < 8) {
        const int d = (tid < 4) ? tid : tid + 1;          // skip center
        const int ny = min(NTILEk - 1, max(0, by + d / 3 - 1));
        const int nx = min(NTILEk - 1, max(0, bx + d % 3 - 1));
        nb = (ny * NTILEk + nx) * 32;
    }

    const int pbase = (gx0 + 4 * w) * PWk + gz0 + ez;  // padded global index
    const int fbase = 4 * w * EXTk + ez;   // buffer row 4w (field row 4w-1)

    // Publish init + entire cone-skipped prefix in one release store.
    // __syncthreads drained every wave's vmcnt (agent-store acks) first.
    __syncthreads();
    if (tid == 0)
        __hip_atomic_store(&done[myid], (unsigned)(kAct + 1),
                           __ATOMIC_RELAXED, __HIP_MEMORY_SCOPE_AGENT);

    // ---- Rounds kAct..31; monotone cone => always active once started ----
    for (int k = kAct; k < NROUNDS; ++k) {
        const int t0 = TBk * k;

        // Wait: 8 neighbors finished round k-1 (reads AND writes). No
        // acquire fence: all cross-block data is read via agent loads.
        if (tid < 8) {
            const unsigned tgt = (unsigned)(k + 1);
            while (__hip_atomic_load(&done[nb], __ATOMIC_RELAXED,
                                     __HIP_MEMORY_SCOPE_AGENT) < tgt)
                __builtin_amdgcn_s_sleep(1);
        }
        __syncthreads();

        float2* __restrict__ Pin  = (k & 1) ? PB : PA;
        float2* __restrict__ Pout = (k & 1) ? PA : PB;

        // Unconditional padded agent loads (apron = zeros forever).
        float2 co[4];
        #pragma unroll
        for (int i = 0; i < 4; ++i) co[i] = ldg_f2(&Pin[pbase + i * PWk]);

        // Unpack + prefill LDS buffer 0.
        float rCur[4], rOld[4];
        #pragma unroll
        for (int i = 0; i < 4; ++i) {
            rCur[i] = co[i].x; rOld[i] = co[i].y;
            sb[0][(4 * w + 1 + i) * EXTk + ez] = rCur[i];
        }

        float sv[TBk];
        if (srcHere) {
            #pragma unroll
            for (int s = 0; s < TBk; ++s) sv[s] = source[t0 + s] * DT2f;
        }

        __syncthreads();

        // ---- 16 sub-steps, fully unrolled, no predication ----
        float rv[TBk];
        #pragma unroll
        for (int s = 0; s < TBk; ++s) {
            const float* cur = sb[s & 1];
            float* nxt = sb[(s & 1) ^ 1];
            // Wave-uniform base + const offsets {0, 5*EXTk} -> ds_read2st64:
            // field rows 4w-1 and 4w+4 at column ez (edge waves hit dummies).
            const float up0 = cur[fbase];
            const float dn3 = cur[fbase + 5 * EXTk];
            float nv[4];
            #pragma unroll
            for (int i = 0; i < 4; ++i) {
                const float up = (i == 0) ? up0 : rCur[i - 1];
                const float dn = (i == 3) ? dn3 : rCur[i + 1];
                const float lf = dpp_shr1(rCur[i]);     // z-1 neighbor
                const float rt = dpp_shl1(rCur[i]);     // z+1 neighbor
                const float sum = (up + dn) + (lf + rt);
                const float t4 = __builtin_fmaf(-4.0f, rCur[i], sum);
                const float pm = __builtin_fmaf(2.0f, rCur[i], -rOld[i]);
                nv[i] = __builtin_fmaf(rV2i[i], t4, pm);
            }
            #pragma unroll
            for (int i = 0; i < 4; ++i) {
                rOld[i] = rCur[i];
                rCur[i] = nv[i];
                nxt[fbase + (1 + i) * EXTk] = nv[i];    // buffer row 4w+1+i
            }
            // Source injection (post-stencil, pre-recording).
            if (srcHere) {
                #pragma unroll
                for (int i = 0; i < 4; ++i) {
                    if (i == (exs & 3)) {
                        rCur[i] += sv[s];
                        nxt[(exs + 1) * EXTk + ezs] = rCur[i];
                    }
                }
            }
            __syncthreads();
            // Receiver sample of field@t0+s (post-injection). Next substep
            // writes the OTHER buffer -> race-free with one barrier.
            if (rOwn) rv[s] = nxt[rIdx];
        }

        // Store interior (rows 16..47 = waves 4..11, lanes 16..47): agent
        // stores -> visible to neighbors' agent loads without any fence.
        if (w >= 4 && w < 12 && ez >= TBk && ez < EXTk - TBk) {
            #pragma unroll
            for (int i = 0; i < 4; ++i)
                stg_f2(&Pout[pbase + i * PWk], make_float2(rCur[i], rOld[i]));
        }

        // Flush receiver buffer (block-private, normal stores).
        if (rOwn) {
            #pragma unroll
            for (int s = 0; s < TBk; ++s)
                out[tid * NSTEPSd + t0 + s] = rv[s];
        }

        // Publish round k. __syncthreads drains every wave's vmcnt (all
        // agent-store acks) before tid 0 can issue the counter store.
        __syncthreads();
        if (tid == 0)
            __hip_atomic_store(&done[myid], (unsigned)(k + 2),
                               __ATOMIC_RELAXED, __HIP_MEMORY_SCOPE_AGENT);
    }
}

extern "C" void kernel_launch(void* const* d_in, const int* in_sizes, int n_in,
                              void* d_out, int out_size, void* d_ws, size_t ws_size,
                              hipStream_t stream) {
    const float* vel    = (const float*)d_in[0];
    const float* source = (const float*)d_in[1];
    const int*   src_x  = (const int*)d_in[2];
    const int*   src_z  = (const int*)d_in[3];
    const int*   rec_x  = (const int*)d_in[4];
    const int*   rec_z  = (const int*)d_in[5];
    float* out = (float*)d_out;

    const size_t FP = (size_t)PWk * PWk;
    float2* PA = (float2*)d_ws;       // padded (cur, old), set A
    float2* PB = PA + FP;             // set B
    unsigned* DONE = (unsigned*)(PB + FP);   // 256 counters, 128B stride

    hipMemsetAsync(DONE, 0, (size_t)NTILEk * NTILEk * 32 * sizeof(unsigned), stream);

    void* args[] = {(void*)&vel, (void*)&source, (void*)&src_x, (void*)&src_z,
                    (void*)&rec_x, (void*)&rec_z, (void*)&PA, (void*)&PB,
                    (void*)&out, (void*)&DONE};
    hipLaunchCooperativeKernel((void*)fdtd_persist, dim3(NTILEk, NTILEk),
                               dim3(1024), args, 0, stream);
}